// Round 8
// baseline (1823.506 us; speedup 1.0000x reference)
//
#include <hip/hip_runtime.h>
#include <stdint.h>

#define HW    480
#define KS    24
#define CH    3
#define HO    457            // 480-24+1
#define NPOS  (HO*HO)        // 208849
#define NP    400
#define PS    (CH*KS*KS)     // 1728
#define SIG   1e-6f
#define NST   108            // exact K16 steps: 1728/16
#define NMT   14             // 32-patch MFMA tiles (448 padded patches)
#define NGRP  1832           // (229 row-pairs * 2 jt) * 4 cw position groups
#define MAXF  8192
#define DELTA 3e-3f          // > worst-case coarse-corr error (~2.1e-3, deterministic bound)

typedef __attribute__((ext_vector_type(8))) short short8;
typedef __attribute__((ext_vector_type(16))) float float16v;
typedef unsigned int uint;
typedef unsigned short ushort;
typedef unsigned long long ull;

static __device__ __forceinline__ ushort f2bf(float v) {
    uint u = __float_as_uint(v);
    uint r = (u + 0x7fffu + ((u >> 16) & 1u)) >> 16;   // RNE
    return (ushort)r;
}
static __device__ __forceinline__ uint mono(float f) {      // order-preserving f32->u32
    uint u = __float_as_uint(f);
    return (u & 0x80000000u) ? ~u : (u | 0x80000000u);
}
static __device__ __forceinline__ float unmono(uint u) {
    uint b = (u & 0x80000000u) ? (u & 0x7fffffffu) : ~u;
    return __uint_as_float(b);
}

// ---------------- prep kernels ----------------

__global__ void repack_k(const float* __restrict__ x, float* __restrict__ Wp) {
    int t = blockIdx.x * 256 + threadIdx.x;
    if (t >= NP * PS) return;
    int p = t / PS, e = t - p * PS;
    int c = e / (KS * KS);
    int r = (e / KS) % KS;
    int w = e % KS;
    int pr = p / 20, pc = p - pr * 20;
    Wp[t] = x[c * HW * HW + (pr * KS + r) * HW + (pc * KS + w)];
}

__global__ void stats_k(const float* __restrict__ Wp,
                        float* __restrict__ meanX, float* __restrict__ denXa) {
    __shared__ float shs[4], shs2[4];
    int p = blockIdx.x;
    float s = 0.f, s2 = 0.f;
    for (int e = threadIdx.x; e < PS; e += 256) {
        float v = Wp[p * PS + e];
        s += v; s2 += v * v;
    }
    for (int o = 32; o > 0; o >>= 1) { s += __shfl_down(s, o); s2 += __shfl_down(s2, o); }
    int lane = threadIdx.x & 63, wv = threadIdx.x >> 6;
    if (lane == 0) { shs[wv] = s; shs2[wv] = s2; }
    __syncthreads();
    if (threadIdx.x == 0) {
        float S = shs[0] + shs[1] + shs[2] + shs[3];
        float S2 = shs2[0] + shs2[1] + shs2[2] + shs2[3];
        float m = S / (float)PS;
        meanX[p] = m;
        denXa[p] = fabsf(S2 / (float)PS - m * m);
    }
}

// y_dec -> bf16 hi plane only (coarse path)
__global__ void ybf_k(const float* __restrict__ y, ushort* __restrict__ yb) {
    int t = blockIdx.x * 256 + threadIdx.x;
    if (t >= CH * HW * HW) return;
    yb[t] = f2bf(y[t]);
}

// Pack A hi fragments (exact K, unshifted): frag f = mtg*108 + s, 512 bf16/frag.
// A[m][k]: m = lane&31, k = (lane>>5)*8 + e, kk = 16s + k (flat [c][kh][kw]).
__global__ void packAh_k(const float* __restrict__ Wp, ushort* __restrict__ Ap) {
    int id = blockIdx.x * 256 + threadIdx.x;
    if (id >= NMT * NST * 512) return;
    int e = id & 7;
    int L = (id >> 3) & 63;
    int f = id >> 9;
    int s = f % NST;
    int mtg = f / NST;
    int kk = s * 16 + (L >> 5) * 8 + e;
    int p = mtg * 32 + (L & 31);
    float v = (p < NP) ? Wp[p * PS + kk] : 0.f;
    Ap[id] = f2bf(v);
}

__global__ void colsum_k(const float* __restrict__ y,
                         float* __restrict__ cs, float* __restrict__ cs2) {
    int t = blockIdx.x * 256 + threadIdx.x;
    if (t >= HO * HW) return;
    int i = t / HW, w = t - i * HW;
    float s = 0.f, s2 = 0.f;
    for (int c = 0; c < CH; c++) {
        const float* base = y + c * HW * HW + i * HW + w;
        for (int dh = 0; dh < KS; dh++) {
            float v = base[dh * HW];
            s += v; s2 += v * v;
        }
    }
    cs[t] = s; cs2[t] = s2;
}

__global__ void window_k(const float* __restrict__ cs, const float* __restrict__ cs2,
                         float* __restrict__ sumY, float* __restrict__ denYa) {
    int t = blockIdx.x * 256 + threadIdx.x;
    if (t >= NPOS) return;
    int i = t / HO, j = t - i * HO;
    const float* r  = cs  + i * HW + j;
    const float* r2 = cs2 + i * HW + j;
    float s = 0.f, s2 = 0.f;
    for (int d = 0; d < KS; d++) { s += r[d]; s2 += r2[d]; }
    sumY[t] = s;
    float ips = 1.0f / (float)PS;
    denYa[t] = fabsf(s2 * ips - (s * ips) * (s * ips));
}

// ---------------- phase1: coarse (bf16-hi) correlation, per-group max ----------------
// grid(2=jt, 229=row-pair, 7=mtg-pair). Block 256 = 4 waves = 4 j-chunks (cw).
// Wave: 64 patches (mt2) x 64 positions (j = j0 + 64cw + 2n + t) x 2 rows (ri).
// B frags read as 32B aligned windows (2x ds_read_b128); lane byte offset is
// 4*(n&3) -> frag0 = dword select, frag1 (t=1) = 16-bit funnel shift.
// One coarse-max table entry per (patch, group); group = ((iy*2+jt)*4+cw).
__launch_bounds__(256, 2)
__global__ void corr1_k(const ushort* __restrict__ ybf, const ushort* __restrict__ Ap,
                        const float* __restrict__ meanX, const float* __restrict__ denXa,
                        const float* __restrict__ sumY, const float* __restrict__ denYa,
                        uint* __restrict__ table) {
    __shared__ ushort Bh[26 * 288];   // 15 KB, one bf16-hi plane

    const int tid  = threadIdx.x;
    const int lane = tid & 63;
    const int cw   = tid >> 6;
    const int n    = lane & 31;
    const int kha  = lane >> 5;
    const int jt   = blockIdx.x;
    const int iy   = blockIdx.y;
    const int mtp  = blockIdx.z;
    const int i0   = iy * 2;
    const int j0   = jt ? 208 : 0;   // 8-aligned; jt1 covers [208,464), j>=457 masked
    const int q0   = n & 3;

    float16v acc[2][2][2];   // [mt][t][ri]
#pragma unroll
    for (int mt = 0; mt < 2; mt++)
#pragma unroll
        for (int t = 0; t < 2; t++)
#pragma unroll
            for (int ri = 0; ri < 2; ri++) acc[mt][t][ri] = (float16v)0.f;

    for (int c = 0; c < CH; c++) {
        __syncthreads();
        // stage 26 rows x 288 cols of bf16-hi y
        for (int it = tid; it < 26 * 36; it += 256) {
            int row = it / 36;
            int g8  = (it - row * 36) * 8;
            int yr  = i0 + row;
            int gj  = j0 + g8;
            uint4 u = make_uint4(0, 0, 0, 0);
            if (yr < HW) {
                const ushort* src = ybf + (c * HW + yr) * HW;
                if (gj + 7 < HW) u = *(const uint4*)(src + gj);
                else {
                    ushort tmp[8];
#pragma unroll
                    for (int e = 0; e < 8; e++) tmp[e] = (gj + e < HW) ? src[gj + e] : (ushort)0;
                    u = *(uint4*)tmp;
                }
            }
            *(uint4*)&Bh[row * 288 + g8] = u;
        }
        __syncthreads();

        for (int q = 0; q < 12; q++) {
#pragma unroll
            for (int u = 0; u < 3; u++) {
                const int s = c * 36 + 3 * q + u;
                short8 ah[2];
#pragma unroll
                for (int mt = 0; mt < 2; mt++)
                    ah[mt] = *(const short8*)(Ap + (((size_t)((mtp * 2 + mt) * NST + s)) << 9) + lane * 8);
                const int rowadd = (u == 0) ? 0 : (u == 1 ? kha : 1);
                const int eoff = (u == 0) ? (kha ? 8 : 0) : (u == 1 ? (kha ? 0 : 16) : (kha ? 16 : 8));
#pragma unroll
                for (int ri = 0; ri < 2; ri++) {
                    const int rL = 2 * q + rowadd + ri;
                    const int abyte = (rL * 288 + 64 * cw + 2 * n + eoff) * 2;   // &15 == 4*q0
                    const uint* wp = (const uint*)((const char*)Bh + (abyte & ~15));
                    uint4 w0 = *(const uint4*)wp;
                    uint4 w1 = *(const uint4*)(wp + 4);
                    uint w[8] = {w0.x, w0.y, w0.z, w0.w, w1.x, w1.y, w1.z, w1.w};
                    uint sel[5];
#pragma unroll
                    for (int jx = 0; jx < 5; jx++) {
                        uint x01 = (q0 & 1) ? w[jx + 1] : w[jx];
                        uint x23 = (q0 & 1) ? w[jx + 3] : w[jx + 2];
                        sel[jx] = (q0 & 2) ? x23 : x01;
                    }
                    union { uint u4[4]; short8 v; } b0, b1;
#pragma unroll
                    for (int ix = 0; ix < 4; ix++) {
                        b0.u4[ix] = sel[ix];
                        b1.u4[ix] = (sel[ix] >> 16) | (sel[ix + 1] << 16);   // +1 bf16 shift (t=1)
                    }
#pragma unroll
                    for (int mt = 0; mt < 2; mt++) {
                        acc[mt][0][ri] = __builtin_amdgcn_mfma_f32_32x32x16_bf16(ah[mt], b0.v, acc[mt][0][ri], 0, 0, 0);
                        acc[mt][1][ri] = __builtin_amdgcn_mfma_f32_32x32x16_bf16(ah[mt], b1.v, acc[mt][1][ri], 0, 0, 0);
                    }
                }
            }
        }
    }

    // ---- epilogue: coarse corr, per-(patch,group) max ----
    const int grp = (iy * 2 + jt) * 4 + cw;
    const float invps = 1.0f / (float)PS;
    float sYv[2][2], dYv[2][2];
#pragma unroll
    for (int ri = 0; ri < 2; ri++) {
        bool iok = (i0 + ri) < HO;
#pragma unroll
        for (int t = 0; t < 2; t++) {
            int j = j0 + 64 * cw + 2 * n + t;
            bool ok = iok && (j < HO);
            sYv[ri][t] = ok ? sumY[(i0 + ri) * HO + j] : 0.f;
            dYv[ri][t] = ok ? denYa[(i0 + ri) * HO + j] : 0.f;
        }
    }
#pragma unroll
    for (int mt = 0; mt < 2; mt++) {
        const int pbase = (mtp * 2 + mt) * 32;
#pragma unroll
        for (int r = 0; r < 16; r++) {
            int p = pbase + (r & 3) + 8 * (r >> 2) + 4 * kha;
            bool pok = p < NP;
            float mX = pok ? meanX[p] : 0.f;
            float dX = pok ? denXa[p] : 0.f;
            uint bu = 0;
#pragma unroll
            for (int t = 0; t < 2; t++)
#pragma unroll
                for (int ri = 0; ri < 2; ri++) {
                    int j = j0 + 64 * cw + 2 * n + t;
                    if ((i0 + ri) < HO && j < HO) {
                        float corr = (2.0f * (acc[mt][t][ri][r] - mX * sYv[ri][t]) * invps + SIG)
                                   / (dX + dYv[ri][t] + SIG);
                        uint uu = mono(corr);
                        bu = uu > bu ? uu : bu;
                    }
                }
#pragma unroll
            for (int o = 1; o < 32; o <<= 1) {
                uint other = __shfl_xor(bu, o);
                bu = other > bu ? other : bu;
            }
            if (n == 0 && pok) table[p * NGRP + grp] = bu;
        }
    }
}

// ---------------- phase2a: per-patch threshold + flagged-group emission ----------------
__global__ void flag_k(const uint* __restrict__ table,
                       uint* __restrict__ flags, uint* __restrict__ cnt) {
    __shared__ uint sm[4];
    __shared__ float sthr;
    int p = blockIdx.x;
    uint m = 0;
    for (int g = threadIdx.x; g < NGRP; g += 256) {
        uint v = table[p * NGRP + g];
        m = v > m ? v : m;
    }
    for (int o = 32; o > 0; o >>= 1) { uint ot = __shfl_down(m, o); m = ot > m ? ot : m; }
    int lane = threadIdx.x & 63, wv = threadIdx.x >> 6;
    if (lane == 0) sm[wv] = m;
    __syncthreads();
    if (threadIdx.x == 0) {
        uint mm = max(max(sm[0], sm[1]), max(sm[2], sm[3]));
        sthr = unmono(mm) - DELTA;
    }
    __syncthreads();
    float thr = sthr;
    for (int g = threadIdx.x; g < NGRP; g += 256) {
        if (unmono(table[p * NGRP + g]) >= thr) {
            uint idx = atomicAdd(cnt, 1u);
            if (idx < MAXF) flags[idx] = (uint)(p * NGRP + g);
        }
    }
}

// ---------------- phase2b: exact fp32 rescoring of flagged groups ----------------
__launch_bounds__(128)
__global__ void rescore_k(const float* __restrict__ Wp, const float* __restrict__ y_dec,
                          const float* __restrict__ meanX, const float* __restrict__ denXa,
                          const float* __restrict__ sumY, const float* __restrict__ denYa,
                          const uint* __restrict__ flags, const uint* __restrict__ cnt,
                          ull* __restrict__ best) {
    __shared__ ull sb[2];
    uint nflag = *cnt; if (nflag > MAXF) nflag = MAXF;
    if (blockIdx.x >= nflag) return;
    uint f = flags[blockIdx.x];
    int p = f / NGRP, grp = f - p * NGRP;
    int cw = grp & 3, pb = grp >> 2;
    int jt = pb & 1, iy = pb >> 1;
    int ri = threadIdx.x >> 6, jo = threadIdx.x & 63;
    int i = iy * 2 + ri;
    int j = (jt ? 208 : 0) + 64 * cw + jo;
    ull pk = 0;
    if (i < HO && j < HO) {
        float dot = 0.f;
        const float* wr = Wp + p * PS;
        for (int c = 0; c < CH; c++)
            for (int kh = 0; kh < KS; kh++) {
                const float* yr = y_dec + ((c * HW) + i + kh) * HW + j;
                const float* wk = wr + (c * KS + kh) * KS;
#pragma unroll
                for (int kw = 0; kw < KS; kw++) dot += wk[kw] * yr[kw];
            }
        float corr = (2.0f * (dot - meanX[p] * sumY[i * HO + j]) * (1.0f / (float)PS) + SIG)
                   / (denXa[p] + denYa[i * HO + j] + SIG);
        uint idx = (uint)(i * HO + j);
        pk = ((ull)mono(corr) << 32) | (uint)(~idx);   // first-max tie-break via ~idx
    }
    for (int o = 32; o > 0; o >>= 1) { ull ot = __shfl_down(pk, o); pk = ot > pk ? ot : pk; }
    if ((threadIdx.x & 63) == 0) sb[threadIdx.x >> 6] = pk;
    __syncthreads();
    if (threadIdx.x == 0) {
        ull m = sb[0] > sb[1] ? sb[0] : sb[1];
        atomicMax(&best[p], m);
    }
}

// ---------------- gather ----------------
__global__ void gather_k(const float* __restrict__ y,
                         const ull* __restrict__ best,
                         float* __restrict__ out) {
    int p = blockIdx.x;
    uint idx = ~((uint)(best[p] & 0xFFFFFFFFull));
    int r = idx / HO, cc = idx - r * HO;
    int pr = p / 20, pc = p - pr * 20;
    for (int e = threadIdx.x; e < PS; e += 256) {
        int c = e / (KS * KS);
        int kh = (e / KS) % KS;
        int kw = e % KS;
        out[c * HW * HW + (pr * KS + kh) * HW + (pc * KS + kw)] =
            y[c * HW * HW + (r + kh) * HW + (cc + kw)];
    }
}

// ---------------- launch ----------------
extern "C" void kernel_launch(void* const* d_in, const int* in_sizes, int n_in,
                              void* d_out, int out_size, void* d_ws, size_t ws_size,
                              hipStream_t stream) {
    const float* x_dec = (const float*)d_in[0];
    const float* y_dec = (const float*)d_in[1];
    const float* y     = (const float*)d_in[2];
    float* out = (float*)d_out;

    char* ws = (char*)d_ws;
    size_t off = 0;
    auto carve = [&](size_t bytes) -> void* {
        void* p = ws + off;
        off += (bytes + 255) & ~(size_t)255;
        return p;
    };
    float*  Wp    = (float*)carve((size_t)NP * PS * 4);           // 2.77 MB
    ushort* ybf   = (ushort*)carve((size_t)CH * HW * HW * 2);     // 1.38 MB
    ushort* Ap    = (ushort*)carve((size_t)NMT * NST * 512 * 2);  // 1.55 MB
    float*  cs    = (float*)carve((size_t)HO * HW * 4);
    float*  cs2   = (float*)carve((size_t)HO * HW * 4);
    float*  sumY  = (float*)carve((size_t)NPOS * 4);
    float*  denYa = (float*)carve((size_t)NPOS * 4);
    float*  meanX = (float*)carve((size_t)NP * 4);
    float*  denXa = (float*)carve((size_t)NP * 4);
    uint*   table = (uint*)carve((size_t)NP * NGRP * 4);          // 2.93 MB
    uint*   flags = (uint*)carve((size_t)MAXF * 4);
    uint*   cnt   = (uint*)carve(256);
    ull*    best  = (ull*)carve((size_t)NP * 8);

    hipMemsetAsync(cnt, 0, 4, stream);
    hipMemsetAsync(best, 0, (size_t)NP * 8, stream);

    repack_k<<<(NP * PS + 255) / 256, 256, 0, stream>>>(x_dec, Wp);
    stats_k<<<NP, 256, 0, stream>>>(Wp, meanX, denXa);
    ybf_k<<<(CH * HW * HW + 255) / 256, 256, 0, stream>>>(y_dec, ybf);
    packAh_k<<<(NMT * NST * 512 + 255) / 256, 256, 0, stream>>>(Wp, Ap);
    colsum_k<<<(HO * HW + 255) / 256, 256, 0, stream>>>(y_dec, cs, cs2);
    window_k<<<(NPOS + 255) / 256, 256, 0, stream>>>(cs, cs2, sumY, denYa);

    dim3 grid(2, 229, 7);
    corr1_k<<<grid, 256, 0, stream>>>(ybf, Ap, meanX, denXa, sumY, denYa, table);

    flag_k<<<NP, 256, 0, stream>>>(table, flags, cnt);
    rescore_k<<<MAXF, 128, 0, stream>>>(Wp, y_dec, meanX, denXa, sumY, denYa, flags, cnt, best);

    gather_k<<<NP, 256, 0, stream>>>(y, best, out);
}

// Round 9
// 540.480 us; speedup vs baseline: 3.3739x; 3.3739x over previous
//
#include <hip/hip_runtime.h>
#include <stdint.h>

#define HW    480
#define KS    24
#define CH    3
#define HO    457            // 480-24+1
#define NPOS  (HO*HO)        // 208849
#define NP    400
#define PS    (CH*KS*KS)     // 1728
#define SIG   1e-6f
#define NST   108            // exact K16 steps: 1728/16
#define NMT   14             // 32-patch MFMA tiles (448 padded patches)
#define NIY   115            // ceil(457/4) row-quads
#define NGRP  (NIY*8*4)      // 3680: (iy,jx,row-in-quad) coarse groups (64 j each)
#define MAXF  16384
#define DELTA 3e-3f          // ~68 sigma of coarse bf16 corr error

typedef __attribute__((ext_vector_type(8))) short short8;
typedef __attribute__((ext_vector_type(16))) float float16v;
typedef unsigned int uint;
typedef unsigned short ushort;
typedef unsigned long long ull;

static __device__ __forceinline__ ushort f2bf(float v) {
    uint u = __float_as_uint(v);
    uint r = (u + 0x7fffu + ((u >> 16) & 1u)) >> 16;   // RNE
    return (ushort)r;
}
static __device__ __forceinline__ uint mono(float f) {      // order-preserving f32->u32
    uint u = __float_as_uint(f);
    return (u & 0x80000000u) ? ~u : (u | 0x80000000u);
}
static __device__ __forceinline__ float unmono(uint u) {
    uint b = (u & 0x80000000u) ? (u & 0x7fffffffu) : ~u;
    return __uint_as_float(b);
}

// ---------------- prep kernels ----------------

__global__ void repack_k(const float* __restrict__ x, float* __restrict__ Wp) {
    int t = blockIdx.x * 256 + threadIdx.x;
    if (t >= NP * PS) return;
    int p = t / PS, e = t - p * PS;
    int c = e / (KS * KS);
    int r = (e / KS) % KS;
    int w = e % KS;
    int pr = p / 20, pc = p - pr * 20;
    Wp[t] = x[c * HW * HW + (pr * KS + r) * HW + (pc * KS + w)];
}

__global__ void stats_k(const float* __restrict__ Wp,
                        float* __restrict__ meanX, float* __restrict__ denXa) {
    __shared__ float shs[4], shs2[4];
    int p = blockIdx.x;
    float s = 0.f, s2 = 0.f;
    for (int e = threadIdx.x; e < PS; e += 256) {
        float v = Wp[p * PS + e];
        s += v; s2 += v * v;
    }
    for (int o = 32; o > 0; o >>= 1) { s += __shfl_down(s, o); s2 += __shfl_down(s2, o); }
    int lane = threadIdx.x & 63, wv = threadIdx.x >> 6;
    if (lane == 0) { shs[wv] = s; shs2[wv] = s2; }
    __syncthreads();
    if (threadIdx.x == 0) {
        float S = shs[0] + shs[1] + shs[2] + shs[3];
        float S2 = shs2[0] + shs2[1] + shs2[2] + shs2[3];
        float m = S / (float)PS;
        meanX[p] = m;
        denXa[p] = fabsf(S2 / (float)PS - m * m);
    }
}

// y_dec -> bf16 hi plane (coarse path)
__global__ void ybf_k(const float* __restrict__ y, ushort* __restrict__ yb) {
    int t = blockIdx.x * 256 + threadIdx.x;
    if (t >= CH * HW * HW) return;
    yb[t] = f2bf(y[t]);
}

// Pack A hi fragments (exact K, unshifted): frag f = mtg*108 + s, 512 bf16/frag.
// A[m][k]: m = lane&31, k = (lane>>5)*8 + e, kk = 16s + k (flat [c][kh][kw]).
// (verbatim from R8 — verified)
__global__ void packAh_k(const float* __restrict__ Wp, ushort* __restrict__ Ap) {
    int id = blockIdx.x * 256 + threadIdx.x;
    if (id >= NMT * NST * 512) return;
    int e = id & 7;
    int L = (id >> 3) & 63;
    int f = id >> 9;
    int s = f % NST;
    int mtg = f / NST;
    int kk = s * 16 + (L >> 5) * 8 + e;
    int p = mtg * 32 + (L & 31);
    float v = (p < NP) ? Wp[p * PS + kk] : 0.f;
    Ap[id] = f2bf(v);
}

__global__ void colsum_k(const float* __restrict__ y,
                         float* __restrict__ cs, float* __restrict__ cs2) {
    int t = blockIdx.x * 256 + threadIdx.x;
    if (t >= HO * HW) return;
    int i = t / HW, w = t - i * HW;
    float s = 0.f, s2 = 0.f;
    for (int c = 0; c < CH; c++) {
        const float* base = y + c * HW * HW + i * HW + w;
        for (int dh = 0; dh < KS; dh++) {
            float v = base[dh * HW];
            s += v; s2 += v * v;
        }
    }
    cs[t] = s; cs2[t] = s2;
}

__global__ void window_k(const float* __restrict__ cs, const float* __restrict__ cs2,
                         float* __restrict__ sumY, float* __restrict__ denYa) {
    int t = blockIdx.x * 256 + threadIdx.x;
    if (t >= NPOS) return;
    int i = t / HO, j = t - i * HO;
    const float* r  = cs  + i * HW + j;
    const float* r2 = cs2 + i * HW + j;
    float s = 0.f, s2 = 0.f;
    for (int d = 0; d < KS; d++) { s += r[d]; s2 += r2[d]; }
    sumY[t] = s;
    float ips = 1.0f / (float)PS;
    denYa[t] = fabsf(s2 * ips - (s * ips) * (s * ips));
}

// ---------------- phase1: coarse bf16-hi correlation, per-group max ----------------
// grid(8=jx, 115=iy, 7=mtp). Block 256 = 4 waves; wave g = output row i0+g.
// Wave: 64 patches (mt2) x 64 positions (j = 64*jx + 2n + t) x 1 row.
// t absorbed into B via a one-ushort-shifted second LDS plane (R7 idiom:
// direct uint reads, no select tree). acc[mt2][t2] = 64 AGPR -> 3 waves/SIMD.
__launch_bounds__(256, 3)
__global__ void corr1_k(const ushort* __restrict__ ybf, const ushort* __restrict__ Ap,
                        const float* __restrict__ meanX, const float* __restrict__ denXa,
                        const float* __restrict__ sumY, const float* __restrict__ denYa,
                        uint* __restrict__ table) {
    __shared__ ushort P0[27 * 160];   // hi plane
    __shared__ ushort P1[27 * 160];   // hi plane shifted by +1 ushort (t=1)

    const int tid  = threadIdx.x;
    const int lane = tid & 63;
    const int g    = tid >> 6;      // wave = row within quad
    const int n    = lane & 31;
    const int kha  = lane >> 5;
    const int jx   = blockIdx.x;
    const int iy   = blockIdx.y;
    const int mtp  = blockIdx.z;
    const int j0   = 64 * jx;
    const int i0   = 4 * iy;
    const int i    = i0 + g;

    // per-(u,kha) LDS offsets: off_u = rowadd*160 + eoff
    const int off0 = kha ? 8   : 0;
    const int off1 = kha ? 160 : 16;
    const int off2 = kha ? 176 : 168;

    const ushort* A0 = Ap + ((size_t)(mtp * 2 + 0) * NST) * 512 + lane * 8;
    const ushort* A1 = Ap + ((size_t)(mtp * 2 + 1) * NST) * 512 + lane * 8;

    float16v acc[2][2];   // [mt][t]
#pragma unroll
    for (int mt = 0; mt < 2; mt++)
#pragma unroll
        for (int t = 0; t < 2; t++) acc[mt][t] = (float16v)0.f;

    for (int c = 0; c < CH; c++) {
        __syncthreads();
        // stage 27 rows x 160 cols: P0 = y rows, P1 = shifted by one pixel
        for (int it = tid; it < 27 * 20; it += 256) {
            int row = it / 20;
            int k8  = (it - row * 20) * 8;
            int yr  = i0 + row;
            int gj  = j0 + k8;
            uint4 a = make_uint4(0, 0, 0, 0);
            uint e8 = 0;
            if (yr < HW) {
                const ushort* src = ybf + (c * HW + yr) * HW;
                if (gj + 8 < HW) {
                    a = *(const uint4*)(src + gj);     // 16B-aligned (gj % 8 == 0)
                    e8 = src[gj + 8];
                } else {
                    ushort tmp[8];
#pragma unroll
                    for (int e = 0; e < 8; e++) tmp[e] = (gj + e < HW) ? src[gj + e] : (ushort)0;
                    a = *(uint4*)tmp;
                    e8 = 0;
                }
            }
            uint4 b;
            b.x = (a.x >> 16) | (a.y << 16);
            b.y = (a.y >> 16) | (a.z << 16);
            b.z = (a.z >> 16) | (a.w << 16);
            b.w = (a.w >> 16) | (e8 << 16);
            *(uint4*)&P0[row * 160 + k8] = a;
            *(uint4*)&P1[row * 160 + k8] = b;
        }
        __syncthreads();

        for (int q = 0; q < 12; q++) {
            const int rbase = (2 * q + g) * 160 + 2 * n;
#pragma unroll
            for (int u = 0; u < 3; u++) {
                const int s = c * 36 + 3 * q + u;
                short8 ah0 = *(const short8*)(A0 + ((size_t)s << 9));
                short8 ah1 = *(const short8*)(A1 + ((size_t)s << 9));
                const int idx = rbase + ((u == 0) ? off0 : (u == 1) ? off1 : off2);
                union { uint u4[4]; short8 v; } b0, b1;
                const uint* p0 = (const uint*)(P0 + idx);
                const uint* p1 = (const uint*)(P1 + idx);
#pragma unroll
                for (int w = 0; w < 4; w++) { b0.u4[w] = p0[w]; b1.u4[w] = p1[w]; }
                acc[0][0] = __builtin_amdgcn_mfma_f32_32x32x16_bf16(ah0, b0.v, acc[0][0], 0, 0, 0);
                acc[0][1] = __builtin_amdgcn_mfma_f32_32x32x16_bf16(ah0, b1.v, acc[0][1], 0, 0, 0);
                acc[1][0] = __builtin_amdgcn_mfma_f32_32x32x16_bf16(ah1, b0.v, acc[1][0], 0, 0, 0);
                acc[1][1] = __builtin_amdgcn_mfma_f32_32x32x16_bf16(ah1, b1.v, acc[1][1], 0, 0, 0);
            }
        }
    }

    // ---- epilogue: coarse corr, per-(patch, group) max ----
    const int grp = (iy * 8 + jx) * 4 + g;
    const float invps = 1.0f / (float)PS;
    const bool iok = i < HO;
    float sYv[2], dYv[2];
#pragma unroll
    for (int t = 0; t < 2; t++) {
        int j = j0 + 2 * n + t;
        bool ok = iok && (j < HO);
        sYv[t] = ok ? sumY[i * HO + j] : 0.f;
        dYv[t] = ok ? denYa[i * HO + j] : 0.f;
    }
#pragma unroll
    for (int mt = 0; mt < 2; mt++) {
        const int pbase = (mtp * 2 + mt) * 32;
#pragma unroll
        for (int r = 0; r < 16; r++) {
            int p = pbase + (r & 3) + 8 * (r >> 2) + 4 * kha;
            bool pok = p < NP;
            float mX = pok ? meanX[p] : 0.f;
            float dX = pok ? denXa[p] : 0.f;
            uint bu = 0;
#pragma unroll
            for (int t = 0; t < 2; t++) {
                int j = j0 + 2 * n + t;
                if (iok && j < HO) {
                    float corr = (2.0f * (acc[mt][t][r] - mX * sYv[t]) * invps + SIG)
                               / (dX + dYv[t] + SIG);
                    uint uu = mono(corr);
                    bu = uu > bu ? uu : bu;
                }
            }
#pragma unroll
            for (int o = 1; o < 32; o <<= 1) {
                uint other = __shfl_xor(bu, o);
                bu = other > bu ? other : bu;
            }
            if (n == 0 && pok) table[p * NGRP + grp] = bu;
        }
    }
}

// ---------------- phase2a: per-patch threshold + flagged-group emission ----------------
__global__ void flag_k(const uint* __restrict__ table,
                       uint* __restrict__ flags, uint* __restrict__ cnt) {
    __shared__ uint sm[4];
    __shared__ float sthr;
    int p = blockIdx.x;
    uint m = 0;
    for (int g = threadIdx.x; g < NGRP; g += 256) {
        uint v = table[p * NGRP + g];
        m = v > m ? v : m;
    }
    for (int o = 32; o > 0; o >>= 1) { uint ot = __shfl_down(m, o); m = ot > m ? ot : m; }
    int lane = threadIdx.x & 63, wv = threadIdx.x >> 6;
    if (lane == 0) sm[wv] = m;
    __syncthreads();
    if (threadIdx.x == 0) {
        uint mm = max(max(sm[0], sm[1]), max(sm[2], sm[3]));
        sthr = unmono(mm) - DELTA;
    }
    __syncthreads();
    float thr = sthr;
    for (int g = threadIdx.x; g < NGRP; g += 256) {
        if (unmono(table[p * NGRP + g]) >= thr) {
            uint idx = atomicAdd(cnt, 1u);
            if (idx < MAXF) flags[idx] = (uint)(p * NGRP + g);
        }
    }
}

// ---------------- phase2b: exact fp32 rescoring of flagged groups ----------------
// One wave per flag; group = 1 row x 64 j.
__launch_bounds__(64)
__global__ void rescore_k(const float* __restrict__ Wp, const float* __restrict__ y_dec,
                          const float* __restrict__ meanX, const float* __restrict__ denXa,
                          const float* __restrict__ sumY, const float* __restrict__ denYa,
                          const uint* __restrict__ flags, const uint* __restrict__ cnt,
                          ull* __restrict__ best) {
    uint nflag = *cnt; if (nflag > MAXF) nflag = MAXF;
    if (blockIdx.x >= nflag) return;
    uint f = flags[blockIdx.x];
    int p = f / NGRP, grp = f - p * NGRP;
    int g = grp & 3, bj = grp >> 2;
    int jx = bj & 7, iy = bj >> 3;
    int i = 4 * iy + g;
    int j = 64 * jx + threadIdx.x;
    ull pk = 0;
    if (i < HO && j < HO) {
        float dot = 0.f;
        const float* wr = Wp + p * PS;
        for (int c = 0; c < CH; c++)
            for (int kh = 0; kh < KS; kh++) {
                const float* yr = y_dec + ((c * HW) + i + kh) * HW + j;
                const float* wk = wr + (c * KS + kh) * KS;
#pragma unroll
                for (int kw = 0; kw < KS; kw++) dot += wk[kw] * yr[kw];
            }
        float corr = (2.0f * (dot - meanX[p] * sumY[i * HO + j]) * (1.0f / (float)PS) + SIG)
                   / (denXa[p] + denYa[i * HO + j] + SIG);
        uint idx = (uint)(i * HO + j);
        pk = ((ull)mono(corr) << 32) | (uint)(~idx);   // first-max tie-break via ~idx
    }
    for (int o = 32; o > 0; o >>= 1) { ull ot = __shfl_down(pk, o); pk = ot > pk ? ot : pk; }
    if (threadIdx.x == 0) atomicMax(&best[p], pk);
}

// ---------------- gather ----------------
__global__ void gather_k(const float* __restrict__ y,
                         const ull* __restrict__ best,
                         float* __restrict__ out) {
    int p = blockIdx.x;
    uint idx = ~((uint)(best[p] & 0xFFFFFFFFull));
    int r = idx / HO, cc = idx - r * HO;
    int pr = p / 20, pc = p - pr * 20;
    for (int e = threadIdx.x; e < PS; e += 256) {
        int c = e / (KS * KS);
        int kh = (e / KS) % KS;
        int kw = e % KS;
        out[c * HW * HW + (pr * KS + kh) * HW + (pc * KS + kw)] =
            y[c * HW * HW + (r + kh) * HW + (cc + kw)];
    }
}

// ---------------- launch ----------------
extern "C" void kernel_launch(void* const* d_in, const int* in_sizes, int n_in,
                              void* d_out, int out_size, void* d_ws, size_t ws_size,
                              hipStream_t stream) {
    const float* x_dec = (const float*)d_in[0];
    const float* y_dec = (const float*)d_in[1];
    const float* y     = (const float*)d_in[2];
    float* out = (float*)d_out;

    char* ws = (char*)d_ws;
    size_t off = 0;
    auto carve = [&](size_t bytes) -> void* {
        void* p = ws + off;
        off += (bytes + 255) & ~(size_t)255;
        return p;
    };
    float*  Wp    = (float*)carve((size_t)NP * PS * 4);           // 2.77 MB
    ushort* ybf   = (ushort*)carve((size_t)CH * HW * HW * 2);     // 1.38 MB
    ushort* Ap    = (ushort*)carve((size_t)NMT * NST * 512 * 2);  // 1.55 MB
    float*  cs    = (float*)carve((size_t)HO * HW * 4);
    float*  cs2   = (float*)carve((size_t)HO * HW * 4);
    float*  sumY  = (float*)carve((size_t)NPOS * 4);
    float*  denYa = (float*)carve((size_t)NPOS * 4);
    float*  meanX = (float*)carve((size_t)NP * 4);
    float*  denXa = (float*)carve((size_t)NP * 4);
    uint*   table = (uint*)carve((size_t)NP * NGRP * 4);          // 5.89 MB
    uint*   flags = (uint*)carve((size_t)MAXF * 4);
    uint*   cnt   = (uint*)carve(256);
    ull*    best  = (ull*)carve((size_t)NP * 8);

    hipMemsetAsync(cnt, 0, 4, stream);
    hipMemsetAsync(best, 0, (size_t)NP * 8, stream);

    repack_k<<<(NP * PS + 255) / 256, 256, 0, stream>>>(x_dec, Wp);
    stats_k<<<NP, 256, 0, stream>>>(Wp, meanX, denXa);
    ybf_k<<<(CH * HW * HW + 255) / 256, 256, 0, stream>>>(y_dec, ybf);
    packAh_k<<<(NMT * NST * 512 + 255) / 256, 256, 0, stream>>>(Wp, Ap);
    colsum_k<<<(HO * HW + 255) / 256, 256, 0, stream>>>(y_dec, cs, cs2);
    window_k<<<(NPOS + 255) / 256, 256, 0, stream>>>(cs, cs2, sumY, denYa);

    dim3 grid(8, NIY, 7);
    corr1_k<<<grid, 256, 0, stream>>>(ybf, Ap, meanX, denXa, sumY, denYa, table);

    flag_k<<<NP, 256, 0, stream>>>(table, flags, cnt);
    rescore_k<<<MAXF, 64, 0, stream>>>(Wp, y_dec, meanX, denXa, sumY, denYa, flags, cnt, best);

    gather_k<<<NP, 256, 0, stream>>>(y, best, out);
}